// Round 1
// 352.224 us; speedup vs baseline: 1.0112x; 1.0112x over previous
//
#include <hip/hip_runtime.h>
#include <hip/hip_bf16.h>

#define D128 128

typedef __attribute__((ext_vector_type(8))) short bf16x8;
typedef __attribute__((ext_vector_type(4))) float f32x4;

__device__ __forceinline__ float b2f(unsigned short u) {
    union { unsigned int i; float f; } z;
    z.i = ((unsigned int)u) << 16;
    return z.f;
}

__device__ __forceinline__ unsigned short f2b(float f) {
    union { float f; unsigned int i; } z;
    z.f = f;
    unsigned int r = z.i + 0x7FFFu + ((z.i >> 16) & 1u);  // round-to-nearest-even
    return (unsigned short)(r >> 16);
}

__device__ __forceinline__ f32x4 mfma16(bf16x8 a, bf16x8 b, f32x4 c) {
    return __builtin_amdgcn_mfma_f32_16x16x32_bf16(a, b, c, 0, 0, 0);
}

// ---------------------------------------------------------------------------
// Kernel 0: convert W1, Wg, W2 (fp32 128x128 each) to bf16 in workspace.
// ---------------------------------------------------------------------------
__global__ void k_cvt(const float* __restrict__ W1,
                      const float* __restrict__ Wg,
                      const float* __restrict__ W2,
                      unsigned short* __restrict__ wbf)
{
    int t = blockIdx.x * blockDim.x + threadIdx.x;
    if (t >= 12288) return;
    const int mat = t / 4096;
    const int idx = (t % 4096) * 4;
    const float* src = mat == 0 ? W1 : (mat == 1 ? Wg : W2);
    float4 f = *(const float4*)(src + idx);
    unsigned short* dst = wbf + mat * 16384 + idx;
    dst[0] = f2b(f.x); dst[1] = f2b(f.y); dst[2] = f2b(f.z); dst[3] = f2b(f.w);
}

// ---------------------------------------------------------------------------
// Kernel 1: fused  y1 = leaky(x,0.01)@W1^T + b1 ; h = y1@Wg^T ; a_src/a_dst
// ---------------------------------------------------------------------------
#define LDST 136  // 128 + 8 bf16 padding

__global__ __launch_bounds__(256) void k_fused_gemm2(
    const float* __restrict__ x,
    const unsigned short* __restrict__ W1b,
    const float* __restrict__ b1,
    const unsigned short* __restrict__ Wgb,
    const float* __restrict__ att_s,
    const float* __restrict__ att_d,
    unsigned short* __restrict__ hfeat,
    float* __restrict__ asrc, float* __restrict__ adst, int N)
{
    __shared__ unsigned short ldsY[128 * LDST];
    const int wave = threadIdx.x >> 6;
    const int lane = threadIdx.x & 63;
    const int lmod = lane & 15;
    const int ldiv = lane >> 4;
    const int rowBase = blockIdx.x * 128;
    const int kOff = ldiv * 8;

    // ---- GEMM1 ----
    f32x4 acc[2][8] = {};
    #pragma unroll
    for (int ks = 0; ks < 4; ++ks) {
        const int kb = ks * 32 + kOff;
        bf16x8 afr[2];
        #pragma unroll
        for (int rt = 0; rt < 2; ++rt) {
            int row = rowBase + wave * 32 + rt * 16 + lmod;
            row = min(row, N - 1);
            const float* px = x + (size_t)row * D128 + kb;
            float4 f0 = *(const float4*)px;
            float4 f1 = *(const float4*)(px + 4);
            float tmp[8] = { f0.x, f0.y, f0.z, f0.w, f1.x, f1.y, f1.z, f1.w };
            union { bf16x8 v; unsigned short s[8]; } o;
            #pragma unroll
            for (int j = 0; j < 8; ++j) {
                float f = tmp[j];
                f = f >= 0.f ? f : 0.01f * f;
                o.s[j] = f2b(f);
            }
            afr[rt] = o.v;
        }
        #pragma unroll
        for (int ct = 0; ct < 8; ++ct) {
            bf16x8 bfr = *(const bf16x8*)(W1b + (size_t)(ct * 16 + lmod) * D128 + kb);
            acc[0][ct] = mfma16(afr[0], bfr, acc[0][ct]);
            acc[1][ct] = mfma16(afr[1], bfr, acc[1][ct]);
        }
    }

    #pragma unroll
    for (int ct = 0; ct < 8; ++ct) {
        const int col = ct * 16 + lmod;
        const float bias = b1[col];
        #pragma unroll
        for (int rt = 0; rt < 2; ++rt)
            #pragma unroll
            for (int r = 0; r < 4; ++r) {
                int rowl = wave * 32 + rt * 16 + ldiv * 4 + r;
                ldsY[rowl * LDST + col] = f2b(acc[rt][ct][r] + bias);
            }
    }
    __syncthreads();

    // ---- GEMM2 ----
    f32x4 acc2[2][8] = {};
    #pragma unroll
    for (int ks = 0; ks < 4; ++ks) {
        const int kb = ks * 32 + kOff;
        bf16x8 afr[2];
        #pragma unroll
        for (int rt = 0; rt < 2; ++rt) {
            int rowl = wave * 32 + rt * 16 + lmod;
            afr[rt] = *(const bf16x8*)&ldsY[rowl * LDST + kb];
        }
        #pragma unroll
        for (int ct = 0; ct < 8; ++ct) {
            bf16x8 bfr = *(const bf16x8*)(Wgb + (size_t)(ct * 16 + lmod) * D128 + kb);
            acc2[0][ct] = mfma16(afr[0], bfr, acc2[0][ct]);
            acc2[1][ct] = mfma16(afr[1], bfr, acc2[1][ct]);
        }
    }

    // store h (bf16)
    #pragma unroll
    for (int ct = 0; ct < 8; ++ct) {
        const int col = ct * 16 + lmod;
        #pragma unroll
        for (int rt = 0; rt < 2; ++rt)
            #pragma unroll
            for (int r = 0; r < 4; ++r) {
                int row = rowBase + wave * 32 + rt * 16 + ldiv * 4 + r;
                if (row < N) hfeat[(size_t)row * D128 + col] = f2b(acc2[rt][ct][r]);
            }
    }

    // fused attention logits
    float attS[8], attD[8];
    #pragma unroll
    for (int ct = 0; ct < 8; ++ct) {
        attS[ct] = att_s[ct * 16 + lmod];
        attD[ct] = att_d[ct * 16 + lmod];
    }
    #pragma unroll
    for (int rt = 0; rt < 2; ++rt) {
        #pragma unroll
        for (int r = 0; r < 4; ++r) {
            float ps[4] = {0.f, 0.f, 0.f, 0.f};
            float pd[4] = {0.f, 0.f, 0.f, 0.f};
            #pragma unroll
            for (int ct = 0; ct < 8; ++ct) {
                const float v = b2f(f2b(acc2[rt][ct][r]));   // bf16-rounded h
                const int hh = ct >> 1;
                ps[hh] += v * attS[ct];
                pd[hh] += v * attD[ct];
            }
            #pragma unroll
            for (int hh = 0; hh < 4; ++hh) {
                #pragma unroll
                for (int off = 1; off < 16; off <<= 1) {
                    ps[hh] += __shfl_xor(ps[hh], off);
                    pd[hh] += __shfl_xor(pd[hh], off);
                }
            }
            const int row = rowBase + wave * 32 + rt * 16 + ldiv * 4 + r;
            if (row < N) {
                if (lmod < 4)            asrc[(size_t)row * 4 + lmod]     = ps[lmod];
                else if (lmod < 8)       adst[(size_t)row * 4 + lmod - 4] = pd[lmod - 4];
            }
        }
    }
}

// ---------------------------------------------------------------------------
// CSR build via coarse-bin counting sort — NO returning global atomics.
// ---------------------------------------------------------------------------
#define CHUNK 8192
#define MAXBINS 512
#define BINCAP 8192

__global__ __launch_bounds__(256) void kA1(
    const int* __restrict__ ei, int* __restrict__ M,
    int E, int B, int nbins)
{
    __shared__ int hist[MAXBINS];
    for (int i = threadIdx.x; i < nbins; i += 256) hist[i] = 0;
    __syncthreads();
    const int base = blockIdx.x * CHUNK;
    const int end = min(base + CHUNK, E);
    for (int e = base + threadIdx.x; e < end; e += 256)
        atomicAdd(&hist[ei[E + e] >> 8], 1);
    __syncthreads();
    for (int i = threadIdx.x; i < nbins; i += 256)
        M[i * B + blockIdx.x] = hist[i];
}

__global__ __launch_bounds__(1024) void k_scan1(
    const int* __restrict__ in, int* __restrict__ scanned,
    int* __restrict__ bsum, int n)
{
    __shared__ int lds[1024];
    const int gid = blockIdx.x * 1024 + threadIdx.x;
    const int v = gid < n ? in[gid] : 0;
    lds[threadIdx.x] = v;
    __syncthreads();
    #pragma unroll
    for (int off = 1; off < 1024; off <<= 1) {
        int t = threadIdx.x >= off ? lds[threadIdx.x - off] : 0;
        __syncthreads();
        lds[threadIdx.x] += t;
        __syncthreads();
    }
    if (gid < n) scanned[gid] = lds[threadIdx.x] - v;   // exclusive (local)
    if (threadIdx.x == 1023) bsum[blockIdx.x] = lds[1023];
}

__global__ __launch_bounds__(1024) void k_scan2(int* __restrict__ bsum, int nb)
{
    __shared__ int lds[1024];
    const int v = threadIdx.x < nb ? bsum[threadIdx.x] : 0;
    lds[threadIdx.x] = v;
    __syncthreads();
    #pragma unroll
    for (int off = 1; off < 1024; off <<= 1) {
        int t = threadIdx.x >= off ? lds[threadIdx.x - off] : 0;
        __syncthreads();
        lds[threadIdx.x] += t;
        __syncthreads();
    }
    if (threadIdx.x < nb) bsum[threadIdx.x] = lds[threadIdx.x] - v;  // exclusive
}

__global__ __launch_bounds__(256) void kA2(
    const int* __restrict__ ei, const int* __restrict__ scanned,
    const int* __restrict__ bsum, int2* __restrict__ binned,
    int E, int B, int nbins)
{
    __shared__ int cursor[MAXBINS];
    for (int i = threadIdx.x; i < nbins; i += 256) {
        const int idx = i * B + blockIdx.x;
        cursor[i] = scanned[idx] + bsum[idx >> 10];
    }
    __syncthreads();
    const int base = blockIdx.x * CHUNK;
    const int end = min(base + CHUNK, E);
    for (int e = base + threadIdx.x; e < end; e += 256) {
        const int s = ei[e], d = ei[E + e];
        const int pos = atomicAdd(&cursor[d >> 8], 1);   // LDS atomic (fast)
        binned[pos] = make_int2(s, d);
    }
}

__global__ __launch_bounds__(256) void kB(
    const int2* __restrict__ binned, const int* __restrict__ scanned,
    const int* __restrict__ bsum, int* __restrict__ bucket,
    int* __restrict__ rowstart, int* __restrict__ rowend,
    int E, int B, int nbins, int N)
{
    __shared__ int2 eb[BINCAP];       // 64 KB
    __shared__ int ldeg[256];
    __shared__ int lscan[256];
    __shared__ int lcur[256];
    const int bin = blockIdx.x;
    const int i0 = bin * B;
    const int binstart = scanned[i0] + bsum[i0 >> 10];
    int binend;
    if (bin + 1 < nbins) {
        const int i1 = (bin + 1) * B;
        binend = scanned[i1] + bsum[i1 >> 10];
    } else {
        binend = E;
    }
    int n = binend - binstart;
    if (n > BINCAP) n = BINCAP;   // statistically impossible; safety clamp

    for (int i = threadIdx.x; i < n; i += 256) eb[i] = binned[binstart + i];
    ldeg[threadIdx.x] = 0;
    __syncthreads();
    for (int i = threadIdx.x; i < n; i += 256)
        atomicAdd(&ldeg[eb[i].y & 255], 1);
    __syncthreads();
    const int v = ldeg[threadIdx.x];
    lscan[threadIdx.x] = v;
    __syncthreads();
    #pragma unroll
    for (int off = 1; off < 256; off <<= 1) {
        int t = threadIdx.x >= off ? lscan[threadIdx.x - off] : 0;
        __syncthreads();
        lscan[threadIdx.x] += t;
        __syncthreads();
    }
    const int excl = lscan[threadIdx.x] - v;
    lcur[threadIdx.x] = excl;
    const int d = (bin << 8) + threadIdx.x;
    if (d < N) {
        rowstart[d] = binstart + excl;
        rowend[d]   = binstart + excl + v;
    }
    __syncthreads();
    for (int i = threadIdx.x; i < n; i += 256) {
        const int lp = atomicAdd(&lcur[eb[i].y & 255], 1);  // LDS atomic
        bucket[binstart + lp] = eb[i].x;
    }
}

// ---------------------------------------------------------------------------
// Kernel 4: GAT aggregation, gather-style.
// NEW LAYOUT: 16 lanes per dst (4 dsts/wave, 16 dsts/block of 256).
//   - each lane owns 8 contiguous channels (16 B) -> hfeat gather is one
//     global_load_dwordx4 per edge-step for the whole 256 B row
//   - attention logit+exp redundancy drops 64 lanes/edge -> 16 lanes/edge
//   - head = gl>>2 (8-ch span never crosses a 32-ch head boundary)
// ---------------------------------------------------------------------------
__global__ __launch_bounds__(256) void k_gat(
    const int* __restrict__ bucket,
    const int* __restrict__ rowstart, const int* __restrict__ rowend,
    const float* __restrict__ asrc, const float* __restrict__ adst,
    const unsigned short* __restrict__ hfeat,
    unsigned short* __restrict__ outbf, int N)
{
    const int wave = threadIdx.x >> 6;
    const int lane = threadIdx.x & 63;
    const int g    = lane >> 4;          // dst-group within wave (0..3)
    const int gl   = lane & 15;          // lane within group
    const int h    = gl >> 2;            // head 0..3
    const int d    = blockIdx.x * 16 + wave * 4 + g;

    int start = 0, end = 0;
    float a_d = 0.f;
    if (d < N) {
        start = rowstart[d];
        end   = rowend[d];
        a_d   = adst[(size_t)d * 4 + h];
    }
    const unsigned int chb = (unsigned int)(gl << 3);   // channel offset (elems)

    float acc[8] = {0.f, 0.f, 0.f, 0.f, 0.f, 0.f, 0.f, 0.f};
    float denom = 0.f;

    int j = start;
    for (; j + 2 <= end; j += 2) {
        const int s0 = bucket[j];
        const int s1 = bucket[j + 1];
        const float as0 = asrc[((size_t)s0 << 2) + h];
        const float as1 = asrc[((size_t)s1 << 2) + h];
        const uint4 hp0 = *(const uint4*)(hfeat + (((unsigned int)s0 << 7) + chb));
        const uint4 hp1 = *(const uint4*)(hfeat + (((unsigned int)s1 << 7) + chb));
        float a0 = as0 + a_d; a0 = a0 >= 0.f ? a0 : 0.2f * a0;
        float a1 = as1 + a_d; a1 = a1 >= 0.f ? a1 : 0.2f * a1;
        const float w0 = __expf(a0), w1 = __expf(a1);
        denom += w0 + w1;
        const unsigned int u00 = hp0.x, u01 = hp0.y, u02 = hp0.z, u03 = hp0.w;
        const unsigned int u10 = hp1.x, u11 = hp1.y, u12 = hp1.z, u13 = hp1.w;
        acc[0] += w0 * b2f((unsigned short)(u00 & 0xFFFFu)) + w1 * b2f((unsigned short)(u10 & 0xFFFFu));
        acc[1] += w0 * b2f((unsigned short)(u00 >> 16))     + w1 * b2f((unsigned short)(u10 >> 16));
        acc[2] += w0 * b2f((unsigned short)(u01 & 0xFFFFu)) + w1 * b2f((unsigned short)(u11 & 0xFFFFu));
        acc[3] += w0 * b2f((unsigned short)(u01 >> 16))     + w1 * b2f((unsigned short)(u11 >> 16));
        acc[4] += w0 * b2f((unsigned short)(u02 & 0xFFFFu)) + w1 * b2f((unsigned short)(u12 & 0xFFFFu));
        acc[5] += w0 * b2f((unsigned short)(u02 >> 16))     + w1 * b2f((unsigned short)(u12 >> 16));
        acc[6] += w0 * b2f((unsigned short)(u03 & 0xFFFFu)) + w1 * b2f((unsigned short)(u13 & 0xFFFFu));
        acc[7] += w0 * b2f((unsigned short)(u03 >> 16))     + w1 * b2f((unsigned short)(u13 >> 16));
    }
    if (j < end) {
        const int s0 = bucket[j];
        const float as0 = asrc[((size_t)s0 << 2) + h];
        const uint4 hp0 = *(const uint4*)(hfeat + (((unsigned int)s0 << 7) + chb));
        float a0 = as0 + a_d; a0 = a0 >= 0.f ? a0 : 0.2f * a0;
        const float w0 = __expf(a0);
        denom += w0;
        acc[0] += w0 * b2f((unsigned short)(hp0.x & 0xFFFFu));
        acc[1] += w0 * b2f((unsigned short)(hp0.x >> 16));
        acc[2] += w0 * b2f((unsigned short)(hp0.y & 0xFFFFu));
        acc[3] += w0 * b2f((unsigned short)(hp0.y >> 16));
        acc[4] += w0 * b2f((unsigned short)(hp0.z & 0xFFFFu));
        acc[5] += w0 * b2f((unsigned short)(hp0.z >> 16));
        acc[6] += w0 * b2f((unsigned short)(hp0.w & 0xFFFFu));
        acc[7] += w0 * b2f((unsigned short)(hp0.w >> 16));
    }

    if (d < N) {
        const float inv = 1.f / (denom + 1e-16f);
        uint4 o;
        o.x = ((unsigned int)f2b(acc[1] * inv) << 16) | f2b(acc[0] * inv);
        o.y = ((unsigned int)f2b(acc[3] * inv) << 16) | f2b(acc[2] * inv);
        o.z = ((unsigned int)f2b(acc[5] * inv) << 16) | f2b(acc[4] * inv);
        o.w = ((unsigned int)f2b(acc[7] * inv) << 16) | f2b(acc[6] * inv);
        *(uint4*)(outbf + (((unsigned int)d << 7) + chb)) = o;
    }
}

// ---------------------------------------------------------------------------
// Kernel 5: out = leaky(gatout + bias_g, 0.01) @ W2^T + b2   (fp32 out)
// ---------------------------------------------------------------------------
__global__ __launch_bounds__(256) void k_final(
    const unsigned short* __restrict__ gatbf,
    const float* __restrict__ bias_g,
    const unsigned short* __restrict__ W2b,
    const float* __restrict__ b2,
    float* __restrict__ out, int N)
{
    const int wave = threadIdx.x >> 6;
    const int lane = threadIdx.x & 63;
    const int lmod = lane & 15;
    const int ldiv = lane >> 4;
    const int rowBase = blockIdx.x * 128;
    const int kOff = ldiv * 8;

    f32x4 acc[2][8] = {};
    #pragma unroll
    for (int ks = 0; ks < 4; ++ks) {
        const int kb = ks * 32 + kOff;
        bf16x8 afr[2];
        #pragma unroll
        for (int rt = 0; rt < 2; ++rt) {
            int row = rowBase + wave * 32 + rt * 16 + lmod;
            row = min(row, N - 1);
            union { uint4 q; unsigned short s[8]; } u;
            u.q = *(const uint4*)(gatbf + (size_t)row * D128 + kb);
            union { bf16x8 v; unsigned short s[8]; } o;
            #pragma unroll
            for (int j = 0; j < 8; ++j) {
                float f = b2f(u.s[j]) + bias_g[kb + j];
                f = f >= 0.f ? f : 0.01f * f;
                o.s[j] = f2b(f);
            }
            afr[rt] = o.v;
        }
        #pragma unroll
        for (int ct = 0; ct < 8; ++ct) {
            bf16x8 bfr = *(const bf16x8*)(W2b + (size_t)(ct * 16 + lmod) * D128 + kb);
            acc[0][ct] = mfma16(afr[0], bfr, acc[0][ct]);
            acc[1][ct] = mfma16(afr[1], bfr, acc[1][ct]);
        }
    }

    #pragma unroll
    for (int ct = 0; ct < 8; ++ct) {
        const int col = ct * 16 + lmod;
        const float bb = b2[col];
        #pragma unroll
        for (int rt = 0; rt < 2; ++rt)
            #pragma unroll
            for (int r = 0; r < 4; ++r) {
                int row = rowBase + wave * 32 + rt * 16 + ldiv * 4 + r;
                if (row < N) out[(size_t)row * D128 + col] = acc[rt][ct][r] + bb;
            }
    }
}

// ---------------------------------------------------------------------------
extern "C" void kernel_launch(void* const* d_in, const int* in_sizes, int n_in,
                              void* d_out, int out_size, void* d_ws, size_t ws_size,
                              hipStream_t stream)
{
    const float* x    = (const float*)d_in[0];
    const int*   ei   = (const int*)d_in[1];
    // d_in[2] edge_type: unused by forward
    const float* W1   = (const float*)d_in[3];
    const float* b1   = (const float*)d_in[4];
    const float* Wg   = (const float*)d_in[5];
    const float* atts = (const float*)d_in[6];
    const float* attd = (const float*)d_in[7];
    const float* bg   = (const float*)d_in[8];
    const float* W2   = (const float*)d_in[9];
    const float* b2   = (const float*)d_in[10];
    float* out = (float*)d_out;

    const int N = in_sizes[0] / D128;
    const int E = in_sizes[1] / 2;

    const int B     = (E + CHUNK - 1) / CHUNK;       // edge chunks
    const int nbins = (N + 255) >> 8;                // coarse bins
    const int nM    = nbins * B;

    // workspace layout (16B aligned pieces)
    char* ws = (char*)d_ws;
    unsigned short* wbf = (unsigned short*)ws;                 // 96 KB
    size_t off = 3 * 16384 * 2;
    unsigned short* hfeat = (unsigned short*)(ws + off); off += (size_t)N * D128 * 2;
    float* asrc = (float*)(ws + off); off += (size_t)N * 4 * 4;
    float* adst = (float*)(ws + off); off += (size_t)N * 4 * 4;
    int* M       = (int*)(ws + off); off += (size_t)nM * 4;
    int* scanned = (int*)(ws + off); off += (size_t)nM * 4;
    int* bsum    = (int*)(ws + off); off += 1024 * 4;
    int2* binned = (int2*)(ws + off); off += (size_t)E * 8;
    int* bucket  = (int*)(ws + off); off += (size_t)E * 4;
    int* rowstart = (int*)(ws + off); off += (size_t)N * 4;
    int* rowend   = (int*)(ws + off); off += (size_t)N * 4;
    unsigned short* outbf = (unsigned short*)(ws + off); off += (size_t)N * D128 * 2;

    k_cvt<<<48, 256, 0, stream>>>(W1, Wg, W2, wbf);

    const int nb = (N + 127) / 128;
    k_fused_gemm2<<<nb, 256, 0, stream>>>(x, wbf, b1, wbf + 16384, atts, attd,
                                          hfeat, asrc, adst, N);

    // CSR build (atomic-free positions)
    kA1<<<B, 256, 0, stream>>>(ei, M, E, B, nbins);
    const int nsb = (nM + 1023) / 1024;
    k_scan1<<<nsb, 1024, 0, stream>>>(M, scanned, bsum, nM);
    k_scan2<<<1, 1024, 0, stream>>>(bsum, nsb);
    kA2<<<B, 256, 0, stream>>>(ei, scanned, bsum, binned, E, B, nbins);
    kB<<<nbins, 256, 0, stream>>>(binned, scanned, bsum, bucket,
                                  rowstart, rowend, E, B, nbins, N);

    // gather-style GAT aggregation (fused softmax), 16 dsts per block
    k_gat<<<(N + 15) / 16, 256, 0, stream>>>(bucket, rowstart, rowend,
                                             asrc, adst, hfeat, outbf, N);

    k_final<<<nb, 256, 0, stream>>>(outbf, bg, wbf + 32768, b2, out, N);
}

// Round 2
// 315.496 us; speedup vs baseline: 1.1289x; 1.1164x over previous
//
#include <hip/hip_runtime.h>
#include <hip/hip_bf16.h>

#define D128 128

typedef __attribute__((ext_vector_type(8))) short bf16x8;
typedef __attribute__((ext_vector_type(4))) float f32x4;

__device__ __forceinline__ float b2f(unsigned short u) {
    union { unsigned int i; float f; } z;
    z.i = ((unsigned int)u) << 16;
    return z.f;
}

__device__ __forceinline__ unsigned short f2b(float f) {
    union { float f; unsigned int i; } z;
    z.f = f;
    unsigned int r = z.i + 0x7FFFu + ((z.i >> 16) & 1u);  // round-to-nearest-even
    return (unsigned short)(r >> 16);
}

__device__ __forceinline__ f32x4 mfma16(bf16x8 a, bf16x8 b, f32x4 c) {
    return __builtin_amdgcn_mfma_f32_16x16x32_bf16(a, b, c, 0, 0, 0);
}

// ---------------------------------------------------------------------------
// Prep 1: blocks 0..63  : compose Wc = Wg @ W1 (fp32), bc = Wg @ b1
//         blocks 64..   : xb = bf16(leaky(x, 0.01))  (streaming)
// ---------------------------------------------------------------------------
#define XBB 1536

__global__ __launch_bounds__(256) void k_prep1(
    const float* __restrict__ x,
    const float* __restrict__ W1, const float* __restrict__ Wg,
    const float* __restrict__ b1,
    float* __restrict__ Wc, float* __restrict__ bc,
    unsigned short* __restrict__ xb, int N)
{
    __shared__ float wgr[256];
    const int t = threadIdx.x;
    if (blockIdx.x < 64) {
        const int i0 = blockIdx.x * 2;
        wgr[t] = Wg[i0 * 128 + t];          // rows i0, i0+1 contiguous
        __syncthreads();
        const int half = t >> 7;
        const int j = t & 127;
        const float* wr = &wgr[half * 128];
        float acc = 0.f;
        #pragma unroll 4
        for (int k = 0; k < 128; ++k)
            acc += wr[k] * W1[k * 128 + j];
        Wc[(i0 + half) * 128 + j] = acc;
        if (j == 0) {
            float ab = 0.f;
            for (int k = 0; k < 128; ++k) ab += wr[k] * b1[k];
            bc[i0 + half] = ab;
        }
    } else {
        const size_t total = (size_t)N * 128;
        const size_t stride = (size_t)XBB * 256 * 8;
        for (size_t i = ((size_t)(blockIdx.x - 64) * 256 + t) * 8; i + 8 <= total; i += stride) {
            float4 f0 = *(const float4*)(x + i);
            float4 f1 = *(const float4*)(x + i + 4);
            float v[8] = { f0.x, f0.y, f0.z, f0.w, f1.x, f1.y, f1.z, f1.w };
            union { uint4 q; unsigned short s[8]; } o;
            #pragma unroll
            for (int jj = 0; jj < 8; ++jj) {
                float f = v[jj];
                f = f >= 0.f ? f : 0.01f * f;
                o.s[jj] = f2b(f);
            }
            *(uint4*)(xb + i) = o.q;
        }
    }
}

// ---------------------------------------------------------------------------
// Prep 2: build fragment-major bf16 weights:
//   Wcat (9 col-tiles x 4 ks x 64 lanes x 8): rows 0..127 = Wc,
//     rows 128..131 = att_src-folded, 132..135 = att_dst-folded, 136..143 = 0
//   W2l  (8 col-tiles), lbias[144] = [bc(128); battS(4); battD(4); 0(8)]
// Fragment index: ((ct*4+ks)*64 + ldiv*16 + lmod)*8 + e
//   holds row (ct*16+lmod), col (ks*32+ldiv*8+e).
// ---------------------------------------------------------------------------
__global__ __launch_bounds__(256) void k_prep2(
    const float* __restrict__ Wc, const float* __restrict__ bc,
    const float* __restrict__ att_s, const float* __restrict__ att_d,
    const float* __restrict__ W2,
    unsigned short* __restrict__ Wcat, unsigned short* __restrict__ W2l,
    float* __restrict__ lbias)
{
    const int b = blockIdx.x, t = threadIdx.x;
    if (b < 9) {
        const int q = b * 256 + t;           // 0..2303
        const int ct = q >> 8, rem = q & 255;
        const int ks = rem >> 6, lane = rem & 63;
        const int ldiv = lane >> 4, lmod = lane & 15;
        const int kb = ks * 32 + ldiv * 8;
        float v[8];
        if (ct < 8) {
            const int rho = ct * 16 + lmod;
            const float4 a = *(const float4*)(Wc + rho * 128 + kb);
            const float4 bq = *(const float4*)(Wc + rho * 128 + kb + 4);
            v[0] = a.x; v[1] = a.y; v[2] = a.z; v[3] = a.w;
            v[4] = bq.x; v[5] = bq.y; v[6] = bq.z; v[7] = bq.w;
        } else {
            #pragma unroll
            for (int e = 0; e < 8; ++e) v[e] = 0.f;
            if (lmod < 8) {
                const int hh = lmod & 3;
                const float* av = lmod < 4 ? att_s : att_d;
                for (int c = 0; c < 32; ++c) {
                    const float w = av[hh * 32 + c];
                    const float* wrow = Wc + (hh * 32 + c) * 128 + kb;
                    #pragma unroll
                    for (int e = 0; e < 8; ++e) v[e] += w * wrow[e];
                }
            }
        }
        union { uint4 qq; unsigned short s[8]; } o;
        #pragma unroll
        for (int e = 0; e < 8; ++e) o.s[e] = f2b(v[e]);
        *(uint4*)(Wcat + q * 8) = o.qq;
    } else if (b < 17) {
        const int q = (b - 9) * 256 + t;     // 0..2047
        const int ct = q >> 8, rem = q & 255;
        const int ks = rem >> 6, lane = rem & 63;
        const int ldiv = lane >> 4, lmod = lane & 15;
        const int kb = ks * 32 + ldiv * 8;
        const int rho = ct * 16 + lmod;
        const float4 a = *(const float4*)(W2 + rho * 128 + kb);
        const float4 bq = *(const float4*)(W2 + rho * 128 + kb + 4);
        union { uint4 qq; unsigned short s[8]; } o;
        o.s[0] = f2b(a.x); o.s[1] = f2b(a.y); o.s[2] = f2b(a.z); o.s[3] = f2b(a.w);
        o.s[4] = f2b(bq.x); o.s[5] = f2b(bq.y); o.s[6] = f2b(bq.z); o.s[7] = f2b(bq.w);
        *(uint4*)(W2l + q * 8) = o.qq;
    } else {
        if (t < 144) {
            float v = 0.f;
            if (t < 128) v = bc[t];
            else if (t < 136) {
                const int hh = (t - 128) & 3;
                const float* av = t < 132 ? att_s : att_d;
                for (int c = 0; c < 32; ++c) v += av[hh * 32 + c] * bc[hh * 32 + c];
            }
            lbias[t] = v;
        }
    }
}

// ---------------------------------------------------------------------------
// Kernel: h(+bias) and attention logits in ONE GEMM: [64 rows] x [144 cols]
//   cols 0..127 -> hfeat (bf16), col-tile 8 (lmod<8) -> asrc/adst (f32)
// ---------------------------------------------------------------------------
__global__ __launch_bounds__(256) void k_gemm_h(
    const unsigned short* __restrict__ xb,
    const unsigned short* __restrict__ Wcat,
    const float* __restrict__ lbias,
    unsigned short* __restrict__ hfeat,
    float* __restrict__ asrc, float* __restrict__ adst, int N)
{
    __shared__ __align__(16) unsigned short sW[18432];   // 36864 B
    const int t = threadIdx.x;
    const int wave = t >> 6, lane = t & 63, lmod = lane & 15, ldiv = lane >> 4;
    const int rowBase = blockIdx.x * 64;

    uint4 w[9];
    #pragma unroll
    for (int r = 0; r < 9; ++r)
        w[r] = *(const uint4*)(Wcat + r * 2048 + t * 8);

    int row = rowBase + wave * 16 + lmod;
    row = min(row, N - 1);
    bf16x8 afr[4];
    #pragma unroll
    for (int ks = 0; ks < 4; ++ks)
        afr[ks] = *(const bf16x8*)(xb + (size_t)row * D128 + ks * 32 + ldiv * 8);

    #pragma unroll
    for (int r = 0; r < 9; ++r)
        *(uint4*)&sW[r * 2048 + t * 8] = w[r];
    __syncthreads();

    f32x4 acc[9] = {};
    #pragma unroll
    for (int ct = 0; ct < 9; ++ct) {
        #pragma unroll
        for (int ks = 0; ks < 4; ++ks) {
            bf16x8 bfr = *(const bf16x8*)&sW[(ct * 256 + ks * 64 + lane) * 8];
            acc[ct] = mfma16(afr[ks], bfr, acc[ct]);
        }
    }

    const int orow = rowBase + wave * 16 + ldiv * 4;
    #pragma unroll
    for (int ct = 0; ct < 8; ++ct) {
        const int col = ct * 16 + lmod;
        const float bias = lbias[col];
        #pragma unroll
        for (int r = 0; r < 4; ++r)
            if (orow + r < N)
                hfeat[(size_t)(orow + r) * D128 + col] = f2b(acc[ct][r] + bias);
    }
    if (lmod < 8) {
        const float lb = lbias[128 + lmod];
        float* dst = lmod < 4 ? asrc : adst;
        const int hh = lmod & 3;
        #pragma unroll
        for (int r = 0; r < 4; ++r)
            if (orow + r < N)
                dst[(size_t)(orow + r) * 4 + hh] = acc[8][r] + lb;
    }
}

// ---------------------------------------------------------------------------
// CSR build via coarse-bin counting sort (unchanged).
// ---------------------------------------------------------------------------
#define CHUNK 8192
#define MAXBINS 512
#define BINCAP 8192

__global__ __launch_bounds__(256) void kA1(
    const int* __restrict__ ei, int* __restrict__ M,
    int E, int B, int nbins)
{
    __shared__ int hist[MAXBINS];
    for (int i = threadIdx.x; i < nbins; i += 256) hist[i] = 0;
    __syncthreads();
    const int base = blockIdx.x * CHUNK;
    const int end = min(base + CHUNK, E);
    for (int e = base + threadIdx.x; e < end; e += 256)
        atomicAdd(&hist[ei[E + e] >> 8], 1);
    __syncthreads();
    for (int i = threadIdx.x; i < nbins; i += 256)
        M[i * B + blockIdx.x] = hist[i];
}

__global__ __launch_bounds__(1024) void k_scan1(
    const int* __restrict__ in, int* __restrict__ scanned,
    int* __restrict__ bsum, int n)
{
    __shared__ int lds[1024];
    const int gid = blockIdx.x * 1024 + threadIdx.x;
    const int v = gid < n ? in[gid] : 0;
    lds[threadIdx.x] = v;
    __syncthreads();
    #pragma unroll
    for (int off = 1; off < 1024; off <<= 1) {
        int t = threadIdx.x >= off ? lds[threadIdx.x - off] : 0;
        __syncthreads();
        lds[threadIdx.x] += t;
        __syncthreads();
    }
    if (gid < n) scanned[gid] = lds[threadIdx.x] - v;   // exclusive (local)
    if (threadIdx.x == 1023) bsum[blockIdx.x] = lds[1023];
}

__global__ __launch_bounds__(1024) void k_scan2(int* __restrict__ bsum, int nb)
{
    __shared__ int lds[1024];
    const int v = threadIdx.x < nb ? bsum[threadIdx.x] : 0;
    lds[threadIdx.x] = v;
    __syncthreads();
    #pragma unroll
    for (int off = 1; off < 1024; off <<= 1) {
        int t = threadIdx.x >= off ? lds[threadIdx.x - off] : 0;
        __syncthreads();
        lds[threadIdx.x] += t;
        __syncthreads();
    }
    if (threadIdx.x < nb) bsum[threadIdx.x] = lds[threadIdx.x] - v;  // exclusive
}

__global__ __launch_bounds__(256) void kA2(
    const int* __restrict__ ei, const int* __restrict__ scanned,
    const int* __restrict__ bsum, int2* __restrict__ binned,
    int E, int B, int nbins)
{
    __shared__ int cursor[MAXBINS];
    for (int i = threadIdx.x; i < nbins; i += 256) {
        const int idx = i * B + blockIdx.x;
        cursor[i] = scanned[idx] + bsum[idx >> 10];
    }
    __syncthreads();
    const int base = blockIdx.x * CHUNK;
    const int end = min(base + CHUNK, E);
    for (int e = base + threadIdx.x; e < end; e += 256) {
        const int s = ei[e], d = ei[E + e];
        const int pos = atomicAdd(&cursor[d >> 8], 1);   // LDS atomic (fast)
        binned[pos] = make_int2(s, d);
    }
}

__global__ __launch_bounds__(256) void kB(
    const int2* __restrict__ binned, const int* __restrict__ scanned,
    const int* __restrict__ bsum, int* __restrict__ bucket,
    int* __restrict__ rowstart, int* __restrict__ rowend,
    int E, int B, int nbins, int N)
{
    __shared__ int2 eb[BINCAP];       // 64 KB
    __shared__ int ldeg[256];
    __shared__ int lscan[256];
    __shared__ int lcur[256];
    const int bin = blockIdx.x;
    const int i0 = bin * B;
    const int binstart = scanned[i0] + bsum[i0 >> 10];
    int binend;
    if (bin + 1 < nbins) {
        const int i1 = (bin + 1) * B;
        binend = scanned[i1] + bsum[i1 >> 10];
    } else {
        binend = E;
    }
    int n = binend - binstart;
    if (n > BINCAP) n = BINCAP;   // statistically impossible; safety clamp

    for (int i = threadIdx.x; i < n; i += 256) eb[i] = binned[binstart + i];
    ldeg[threadIdx.x] = 0;
    __syncthreads();
    for (int i = threadIdx.x; i < n; i += 256)
        atomicAdd(&ldeg[eb[i].y & 255], 1);
    __syncthreads();
    const int v = ldeg[threadIdx.x];
    lscan[threadIdx.x] = v;
    __syncthreads();
    #pragma unroll
    for (int off = 1; off < 256; off <<= 1) {
        int t = threadIdx.x >= off ? lscan[threadIdx.x - off] : 0;
        __syncthreads();
        lscan[threadIdx.x] += t;
        __syncthreads();
    }
    const int excl = lscan[threadIdx.x] - v;
    lcur[threadIdx.x] = excl;
    const int d = (bin << 8) + threadIdx.x;
    if (d < N) {
        rowstart[d] = binstart + excl;
        rowend[d]   = binstart + excl + v;
    }
    __syncthreads();
    for (int i = threadIdx.x; i < n; i += 256) {
        const int lp = atomicAdd(&lcur[eb[i].y & 255], 1);  // LDS atomic
        bucket[binstart + lp] = eb[i].x;
    }
}

// ---------------------------------------------------------------------------
// GAT aggregation, 16 lanes per dst; epilogue bakes +bias_g and leaky(0.01)
// so k_final's A-operand is load-only bf16.
// ---------------------------------------------------------------------------
__global__ __launch_bounds__(256) void k_gat(
    const int* __restrict__ bucket,
    const int* __restrict__ rowstart, const int* __restrict__ rowend,
    const float* __restrict__ asrc, const float* __restrict__ adst,
    const unsigned short* __restrict__ hfeat,
    const float* __restrict__ bias_g,
    unsigned short* __restrict__ outbf, int N)
{
    const int wave = threadIdx.x >> 6;
    const int lane = threadIdx.x & 63;
    const int g    = lane >> 4;          // dst-group within wave (0..3)
    const int gl   = lane & 15;          // lane within group
    const int h    = gl >> 2;            // head 0..3
    const int d    = blockIdx.x * 16 + wave * 4 + g;

    int start = 0, end = 0;
    float a_d = 0.f;
    if (d < N) {
        start = rowstart[d];
        end   = rowend[d];
        a_d   = adst[(size_t)d * 4 + h];
    }
    const unsigned int chb = (unsigned int)(gl << 3);   // channel offset (elems)

    float acc[8] = {0.f, 0.f, 0.f, 0.f, 0.f, 0.f, 0.f, 0.f};
    float denom = 0.f;

    int j = start;
    for (; j + 2 <= end; j += 2) {
        const int s0 = bucket[j];
        const int s1 = bucket[j + 1];
        const float as0 = asrc[((size_t)s0 << 2) + h];
        const float as1 = asrc[((size_t)s1 << 2) + h];
        const uint4 hp0 = *(const uint4*)(hfeat + (((unsigned int)s0 << 7) + chb));
        const uint4 hp1 = *(const uint4*)(hfeat + (((unsigned int)s1 << 7) + chb));
        float a0 = as0 + a_d; a0 = a0 >= 0.f ? a0 : 0.2f * a0;
        float a1 = as1 + a_d; a1 = a1 >= 0.f ? a1 : 0.2f * a1;
        const float w0 = __expf(a0), w1 = __expf(a1);
        denom += w0 + w1;
        const unsigned int u00 = hp0.x, u01 = hp0.y, u02 = hp0.z, u03 = hp0.w;
        const unsigned int u10 = hp1.x, u11 = hp1.y, u12 = hp1.z, u13 = hp1.w;
        acc[0] += w0 * b2f((unsigned short)(u00 & 0xFFFFu)) + w1 * b2f((unsigned short)(u10 & 0xFFFFu));
        acc[1] += w0 * b2f((unsigned short)(u00 >> 16))     + w1 * b2f((unsigned short)(u10 >> 16));
        acc[2] += w0 * b2f((unsigned short)(u01 & 0xFFFFu)) + w1 * b2f((unsigned short)(u11 & 0xFFFFu));
        acc[3] += w0 * b2f((unsigned short)(u01 >> 16))     + w1 * b2f((unsigned short)(u11 >> 16));
        acc[4] += w0 * b2f((unsigned short)(u02 & 0xFFFFu)) + w1 * b2f((unsigned short)(u12 & 0xFFFFu));
        acc[5] += w0 * b2f((unsigned short)(u02 >> 16))     + w1 * b2f((unsigned short)(u12 >> 16));
        acc[6] += w0 * b2f((unsigned short)(u03 & 0xFFFFu)) + w1 * b2f((unsigned short)(u13 & 0xFFFFu));
        acc[7] += w0 * b2f((unsigned short)(u03 >> 16))     + w1 * b2f((unsigned short)(u13 >> 16));
    }
    if (j < end) {
        const int s0 = bucket[j];
        const float as0 = asrc[((size_t)s0 << 2) + h];
        const uint4 hp0 = *(const uint4*)(hfeat + (((unsigned int)s0 << 7) + chb));
        float a0 = as0 + a_d; a0 = a0 >= 0.f ? a0 : 0.2f * a0;
        const float w0 = __expf(a0);
        denom += w0;
        acc[0] += w0 * b2f((unsigned short)(hp0.x & 0xFFFFu));
        acc[1] += w0 * b2f((unsigned short)(hp0.x >> 16));
        acc[2] += w0 * b2f((unsigned short)(hp0.y & 0xFFFFu));
        acc[3] += w0 * b2f((unsigned short)(hp0.y >> 16));
        acc[4] += w0 * b2f((unsigned short)(hp0.z & 0xFFFFu));
        acc[5] += w0 * b2f((unsigned short)(hp0.z >> 16));
        acc[6] += w0 * b2f((unsigned short)(hp0.w & 0xFFFFu));
        acc[7] += w0 * b2f((unsigned short)(hp0.w >> 16));
    }

    if (d < N) {
        const float inv = 1.f / (denom + 1e-16f);
        const float4 bg0 = *(const float4*)(bias_g + chb);
        const float4 bg1 = *(const float4*)(bias_g + chb + 4);
        const float bg[8] = { bg0.x, bg0.y, bg0.z, bg0.w, bg1.x, bg1.y, bg1.z, bg1.w };
        unsigned short s[8];
        #pragma unroll
        for (int k2 = 0; k2 < 8; ++k2) {
            float v = acc[k2] * inv + bg[k2];
            v = v >= 0.f ? v : 0.01f * v;
            s[k2] = f2b(v);
        }
        uint4 o;
        o.x = ((unsigned int)s[1] << 16) | s[0];
        o.y = ((unsigned int)s[3] << 16) | s[2];
        o.z = ((unsigned int)s[5] << 16) | s[4];
        o.w = ((unsigned int)s[7] << 16) | s[6];
        *(uint4*)(outbf + (((unsigned int)d << 7) + chb)) = o;
    }
}

// ---------------------------------------------------------------------------
// Final GEMM: out = outbf @ W2^T + b2  (A already has bias+leaky baked in)
// ---------------------------------------------------------------------------
__global__ __launch_bounds__(256) void k_final(
    const unsigned short* __restrict__ gatbf,
    const unsigned short* __restrict__ W2l,
    const float* __restrict__ b2,
    float* __restrict__ out, int N)
{
    __shared__ __align__(16) unsigned short sW[16384];   // 32768 B
    const int t = threadIdx.x;
    const int wave = t >> 6, lane = t & 63, lmod = lane & 15, ldiv = lane >> 4;
    const int rowBase = blockIdx.x * 64;

    uint4 w[8];
    #pragma unroll
    for (int r = 0; r < 8; ++r)
        w[r] = *(const uint4*)(W2l + r * 2048 + t * 8);

    int row = rowBase + wave * 16 + lmod;
    row = min(row, N - 1);
    bf16x8 afr[4];
    #pragma unroll
    for (int ks = 0; ks < 4; ++ks)
        afr[ks] = *(const bf16x8*)(gatbf + (size_t)row * D128 + ks * 32 + ldiv * 8);

    #pragma unroll
    for (int r = 0; r < 8; ++r)
        *(uint4*)&sW[r * 2048 + t * 8] = w[r];
    __syncthreads();

    f32x4 acc[8] = {};
    #pragma unroll
    for (int ct = 0; ct < 8; ++ct) {
        #pragma unroll
        for (int ks = 0; ks < 4; ++ks) {
            bf16x8 bfr = *(const bf16x8*)&sW[(ct * 256 + ks * 64 + lane) * 8];
            acc[ct] = mfma16(afr[ks], bfr, acc[ct]);
        }
    }

    const int orow = rowBase + wave * 16 + ldiv * 4;
    #pragma unroll
    for (int ct = 0; ct < 8; ++ct) {
        const int col = ct * 16 + lmod;
        const float bb = b2[col];
        #pragma unroll
        for (int r = 0; r < 4; ++r)
            if (orow + r < N)
                out[(size_t)(orow + r) * D128 + col] = acc[ct][r] + bb;
    }
}

// ---------------------------------------------------------------------------
extern "C" void kernel_launch(void* const* d_in, const int* in_sizes, int n_in,
                              void* d_out, int out_size, void* d_ws, size_t ws_size,
                              hipStream_t stream)
{
    const float* x    = (const float*)d_in[0];
    const int*   ei   = (const int*)d_in[1];
    // d_in[2] edge_type: unused by forward
    const float* W1   = (const float*)d_in[3];
    const float* b1   = (const float*)d_in[4];
    const float* Wg   = (const float*)d_in[5];
    const float* atts = (const float*)d_in[6];
    const float* attd = (const float*)d_in[7];
    const float* bg   = (const float*)d_in[8];
    const float* W2   = (const float*)d_in[9];
    const float* b2   = (const float*)d_in[10];
    float* out = (float*)d_out;

    const int N = in_sizes[0] / D128;
    const int E = in_sizes[1] / 2;

    const int B     = (E + CHUNK - 1) / CHUNK;       // edge chunks
    const int nbins = (N + 255) >> 8;                // coarse bins
    const int nM    = nbins * B;

    // workspace layout (16B aligned pieces)
    char* ws = (char*)d_ws;
    float* Wc = (float*)ws;                                    // 64 KB
    size_t off = 65536;
    float* bc    = (float*)(ws + off); off += 512;
    float* lbias = (float*)(ws + off); off += 1024;
    unsigned short* Wcat = (unsigned short*)(ws + off); off += 36864;
    unsigned short* W2l  = (unsigned short*)(ws + off); off += 32768;
    unsigned short* xb   = (unsigned short*)(ws + off); off += (size_t)N * D128 * 2;
    unsigned short* hfeat = (unsigned short*)(ws + off); off += (size_t)N * D128 * 2;
    float* asrc = (float*)(ws + off); off += (size_t)N * 4 * 4;
    float* adst = (float*)(ws + off); off += (size_t)N * 4 * 4;
    int* M       = (int*)(ws + off); off += (size_t)nM * 4;
    int* scanned = (int*)(ws + off); off += (size_t)nM * 4;
    int* bsum    = (int*)(ws + off); off += 1024 * 4;
    int2* binned = (int2*)(ws + off); off += (size_t)E * 8;
    int* bucket  = (int*)(ws + off); off += (size_t)E * 4;
    int* rowstart = (int*)(ws + off); off += (size_t)N * 4;
    int* rowend   = (int*)(ws + off); off += (size_t)N * 4;
    unsigned short* outbf = (unsigned short*)(ws + off); off += (size_t)N * D128 * 2;

    // prep: compose weights + bf16(leaky(x))
    k_prep1<<<64 + XBB, 256, 0, stream>>>(x, W1, Wg, b1, Wc, bc, xb, N);
    k_prep2<<<18, 256, 0, stream>>>(Wc, bc, atts, attd, W2, Wcat, W2l, lbias);

    // single fused GEMM: h + logits
    const int nbg = (N + 63) / 64;
    k_gemm_h<<<nbg, 256, 0, stream>>>(xb, Wcat, lbias, hfeat, asrc, adst, N);

    // CSR build (atomic-free positions)
    kA1<<<B, 256, 0, stream>>>(ei, M, E, B, nbins);
    const int nsb = (nM + 1023) / 1024;
    k_scan1<<<nsb, 1024, 0, stream>>>(M, scanned, bsum, nM);
    k_scan2<<<1, 1024, 0, stream>>>(bsum, nsb);
    kA2<<<B, 256, 0, stream>>>(ei, scanned, bsum, binned, E, B, nbins);
    kB<<<nbins, 256, 0, stream>>>(binned, scanned, bsum, bucket,
                                  rowstart, rowend, E, B, nbins, N);

    // gather-style GAT aggregation (fused softmax + bias_g + leaky)
    k_gat<<<(N + 15) / 16, 256, 0, stream>>>(bucket, rowstart, rowend,
                                             asrc, adst, hfeat, bg, outbf, N);

    k_final<<<nbg, 256, 0, stream>>>(outbf, W2l, b2, out, N);
}

// Round 3
// 302.609 us; speedup vs baseline: 1.1770x; 1.0426x over previous
//
#include <hip/hip_runtime.h>
#include <hip/hip_bf16.h>

#define D128 128

typedef __attribute__((ext_vector_type(8))) short bf16x8;
typedef __attribute__((ext_vector_type(4))) float f32x4;

__device__ __forceinline__ float b2f(unsigned short u) {
    union { unsigned int i; float f; } z;
    z.i = ((unsigned int)u) << 16;
    return z.f;
}

__device__ __forceinline__ unsigned short f2b(float f) {
    union { float f; unsigned int i; } z;
    z.f = f;
    unsigned int r = z.i + 0x7FFFu + ((z.i >> 16) & 1u);  // round-to-nearest-even
    return (unsigned short)(r >> 16);
}

__device__ __forceinline__ f32x4 mfma16(bf16x8 a, bf16x8 b, f32x4 c) {
    return __builtin_amdgcn_mfma_f32_16x16x32_bf16(a, b, c, 0, 0, 0);
}

#define CHUNK 8192
#define MAXBINS 512
#define BINCAP 8192
#define XBB 1536

// ---------------------------------------------------------------------------
// Prep 1 (3-way block partition):
//   blocks [0,64)        : compose Wc = Wg @ W1 (fp32), bc = Wg @ b1
//   blocks [64,64+B)     : kA1 per-chunk dst histogram -> M[bin*B + chunk]
//   blocks [64+B, ...)   : xb = bf16(leaky(x, 0.01))  (streaming)
// ---------------------------------------------------------------------------
__global__ __launch_bounds__(256) void k_prep1(
    const float* __restrict__ x,
    const float* __restrict__ W1, const float* __restrict__ Wg,
    const float* __restrict__ b1,
    const int* __restrict__ ei, int* __restrict__ M,
    float* __restrict__ Wc, float* __restrict__ bc,
    unsigned short* __restrict__ xb,
    int N, int E, int B, int nbins)
{
    __shared__ float wgr[256];
    __shared__ int hist[MAXBINS];
    const int t = threadIdx.x;
    if (blockIdx.x < 64) {
        const int i0 = blockIdx.x * 2;
        wgr[t] = Wg[i0 * 128 + t];          // rows i0, i0+1 contiguous
        __syncthreads();
        const int half = t >> 7;
        const int j = t & 127;
        const float* wr = &wgr[half * 128];
        float acc = 0.f;
        #pragma unroll 4
        for (int k = 0; k < 128; ++k)
            acc += wr[k] * W1[k * 128 + j];
        Wc[(i0 + half) * 128 + j] = acc;
        if (j == 0) {
            float ab = 0.f;
            for (int k = 0; k < 128; ++k) ab += wr[k] * b1[k];
            bc[i0 + half] = ab;
        }
    } else if (blockIdx.x < 64 + B) {
        const int chunk = blockIdx.x - 64;
        for (int i = t; i < nbins; i += 256) hist[i] = 0;
        __syncthreads();
        const int base = chunk * CHUNK;
        const int end = min(base + CHUNK, E);
        for (int e = base + t; e < end; e += 256)
            atomicAdd(&hist[ei[E + e] >> 8], 1);
        __syncthreads();
        for (int i = t; i < nbins; i += 256)
            M[i * B + chunk] = hist[i];
    } else {
        const size_t total = (size_t)N * 128;
        const size_t stride = (size_t)XBB * 256 * 8;
        for (size_t i = ((size_t)(blockIdx.x - 64 - B) * 256 + t) * 8; i + 8 <= total; i += stride) {
            float4 f0 = *(const float4*)(x + i);
            float4 f1 = *(const float4*)(x + i + 4);
            float v[8] = { f0.x, f0.y, f0.z, f0.w, f1.x, f1.y, f1.z, f1.w };
            union { uint4 q; unsigned short s[8]; } o;
            #pragma unroll
            for (int jj = 0; jj < 8; ++jj) {
                float f = v[jj];
                f = f >= 0.f ? f : 0.01f * f;
                o.s[jj] = f2b(f);
            }
            *(uint4*)(xb + i) = o.q;
        }
    }
}

// ---------------------------------------------------------------------------
// Prep 2: build fragment-major bf16 weights (unchanged).
// ---------------------------------------------------------------------------
__global__ __launch_bounds__(256) void k_prep2(
    const float* __restrict__ Wc, const float* __restrict__ bc,
    const float* __restrict__ att_s, const float* __restrict__ att_d,
    const float* __restrict__ W2,
    unsigned short* __restrict__ Wcat, unsigned short* __restrict__ W2l,
    float* __restrict__ lbias)
{
    const int b = blockIdx.x, t = threadIdx.x;
    if (b < 9) {
        const int q = b * 256 + t;           // 0..2303
        const int ct = q >> 8, rem = q & 255;
        const int ks = rem >> 6, lane = rem & 63;
        const int ldiv = lane >> 4, lmod = lane & 15;
        const int kb = ks * 32 + ldiv * 8;
        float v[8];
        if (ct < 8) {
            const int rho = ct * 16 + lmod;
            const float4 a = *(const float4*)(Wc + rho * 128 + kb);
            const float4 bq = *(const float4*)(Wc + rho * 128 + kb + 4);
            v[0] = a.x; v[1] = a.y; v[2] = a.z; v[3] = a.w;
            v[4] = bq.x; v[5] = bq.y; v[6] = bq.z; v[7] = bq.w;
        } else {
            #pragma unroll
            for (int e = 0; e < 8; ++e) v[e] = 0.f;
            if (lmod < 8) {
                const int hh = lmod & 3;
                const float* av = lmod < 4 ? att_s : att_d;
                for (int c = 0; c < 32; ++c) {
                    const float w = av[hh * 32 + c];
                    const float* wrow = Wc + (hh * 32 + c) * 128 + kb;
                    #pragma unroll
                    for (int e = 0; e < 8; ++e) v[e] += w * wrow[e];
                }
            }
        }
        union { uint4 qq; unsigned short s[8]; } o;
        #pragma unroll
        for (int e = 0; e < 8; ++e) o.s[e] = f2b(v[e]);
        *(uint4*)(Wcat + q * 8) = o.qq;
    } else if (b < 17) {
        const int q = (b - 9) * 256 + t;     // 0..2047
        const int ct = q >> 8, rem = q & 255;
        const int ks = rem >> 6, lane = rem & 63;
        const int ldiv = lane >> 4, lmod = lane & 15;
        const int kb = ks * 32 + ldiv * 8;
        const int rho = ct * 16 + lmod;
        const float4 a = *(const float4*)(W2 + rho * 128 + kb);
        const float4 bq = *(const float4*)(W2 + rho * 128 + kb + 4);
        union { uint4 qq; unsigned short s[8]; } o;
        o.s[0] = f2b(a.x); o.s[1] = f2b(a.y); o.s[2] = f2b(a.z); o.s[3] = f2b(a.w);
        o.s[4] = f2b(bq.x); o.s[5] = f2b(bq.y); o.s[6] = f2b(bq.z); o.s[7] = f2b(bq.w);
        *(uint4*)(W2l + q * 8) = o.qq;
    } else {
        if (t < 144) {
            float v = 0.f;
            if (t < 128) v = bc[t];
            else if (t < 136) {
                const int hh = (t - 128) & 3;
                const float* av = t < 132 ? att_s : att_d;
                for (int c = 0; c < 32; ++c) v += av[hh * 32 + c] * bc[hh * 32 + c];
            }
            lbias[t] = v;
        }
    }
}

// ---------------------------------------------------------------------------
// h(+bias) and attention logits in ONE GEMM (unchanged).
// ---------------------------------------------------------------------------
__global__ __launch_bounds__(256) void k_gemm_h(
    const unsigned short* __restrict__ xb,
    const unsigned short* __restrict__ Wcat,
    const float* __restrict__ lbias,
    unsigned short* __restrict__ hfeat,
    float* __restrict__ asrc, float* __restrict__ adst, int N)
{
    __shared__ __align__(16) unsigned short sW[18432];   // 36864 B
    const int t = threadIdx.x;
    const int wave = t >> 6, lane = t & 63, lmod = lane & 15, ldiv = lane >> 4;
    const int rowBase = blockIdx.x * 64;

    uint4 w[9];
    #pragma unroll
    for (int r = 0; r < 9; ++r)
        w[r] = *(const uint4*)(Wcat + r * 2048 + t * 8);

    int row = rowBase + wave * 16 + lmod;
    row = min(row, N - 1);
    bf16x8 afr[4];
    #pragma unroll
    for (int ks = 0; ks < 4; ++ks)
        afr[ks] = *(const bf16x8*)(xb + (size_t)row * D128 + ks * 32 + ldiv * 8);

    #pragma unroll
    for (int r = 0; r < 9; ++r)
        *(uint4*)&sW[r * 2048 + t * 8] = w[r];
    __syncthreads();

    f32x4 acc[9] = {};
    #pragma unroll
    for (int ct = 0; ct < 9; ++ct) {
        #pragma unroll
        for (int ks = 0; ks < 4; ++ks) {
            bf16x8 bfr = *(const bf16x8*)&sW[(ct * 256 + ks * 64 + lane) * 8];
            acc[ct] = mfma16(afr[ks], bfr, acc[ct]);
        }
    }

    const int orow = rowBase + wave * 16 + ldiv * 4;
    #pragma unroll
    for (int ct = 0; ct < 8; ++ct) {
        const int col = ct * 16 + lmod;
        const float bias = lbias[col];
        #pragma unroll
        for (int r = 0; r < 4; ++r)
            if (orow + r < N)
                hfeat[(size_t)(orow + r) * D128 + col] = f2b(acc[ct][r] + bias);
    }
    if (lmod < 8) {
        const float lb = lbias[128 + lmod];
        float* dst = lmod < 4 ? asrc : adst;
        const int hh = lmod & 3;
        #pragma unroll
        for (int r = 0; r < 4; ++r)
            if (orow + r < N)
                dst[(size_t)(orow + r) * 4 + hh] = acc[8][r] + lb;
    }
}

// ---------------------------------------------------------------------------
// Scan of per-chunk histograms (block-local; block sums to bsum, raw).
// ---------------------------------------------------------------------------
__global__ __launch_bounds__(1024) void k_scan1(
    const int* __restrict__ in, int* __restrict__ scanned,
    int* __restrict__ bsum, int n)
{
    __shared__ int lds[1024];
    const int gid = blockIdx.x * 1024 + threadIdx.x;
    const int v = gid < n ? in[gid] : 0;
    lds[threadIdx.x] = v;
    __syncthreads();
    #pragma unroll
    for (int off = 1; off < 1024; off <<= 1) {
        int t = threadIdx.x >= off ? lds[threadIdx.x - off] : 0;
        __syncthreads();
        lds[threadIdx.x] += t;
        __syncthreads();
    }
    if (gid < n) scanned[gid] = lds[threadIdx.x] - v;   // exclusive (local)
    if (threadIdx.x == 1023) bsum[blockIdx.x] = lds[1023];
}

// ---------------------------------------------------------------------------
// kA2: scatter (src,dst) into bin regions. Computes bsum prefix locally.
// ---------------------------------------------------------------------------
__global__ __launch_bounds__(256) void kA2(
    const int* __restrict__ ei, const int* __restrict__ scanned,
    const int* __restrict__ bsum, int2* __restrict__ binned,
    int E, int B, int nbins, int nM)
{
    __shared__ int cursor[MAXBINS];
    __shared__ int bpre[1024];
    const int nsb = (nM + 1023) >> 10;
    for (int i = threadIdx.x; i < nsb; i += 256) bpre[i] = bsum[i];
    __syncthreads();
    if (threadIdx.x == 0) {
        int run = 0;
        for (int i = 0; i < nsb; ++i) { int tv = bpre[i]; bpre[i] = run; run += tv; }
    }
    __syncthreads();
    for (int i = threadIdx.x; i < nbins; i += 256) {
        const int idx = i * B + blockIdx.x;
        cursor[i] = scanned[idx] + bpre[idx >> 10];
    }
    __syncthreads();
    const int base = blockIdx.x * CHUNK;
    const int end = min(base + CHUNK, E);
    for (int e = base + threadIdx.x; e < end; e += 256) {
        const int s = ei[e], d = ei[E + e];
        const int pos = atomicAdd(&cursor[d >> 8], 1);   // LDS atomic (fast)
        binned[pos] = make_int2(s, d);
    }
}

// ---------------------------------------------------------------------------
// kB: per-bin local CSR in LDS -> bucket + rowstart/rowend. Local bsum prefix.
// ---------------------------------------------------------------------------
__global__ __launch_bounds__(256) void kB(
    const int2* __restrict__ binned, const int* __restrict__ scanned,
    const int* __restrict__ bsum, int* __restrict__ bucket,
    int* __restrict__ rowstart, int* __restrict__ rowend,
    int E, int B, int nbins, int N, int nM)
{
    __shared__ int2 eb[BINCAP];       // 64 KB
    __shared__ int ldeg[256];
    __shared__ int lscan[256];
    __shared__ int lcur[256];
    __shared__ int bpre[1024];
    const int nsb = (nM + 1023) >> 10;
    for (int i = threadIdx.x; i < nsb; i += 256) bpre[i] = bsum[i];
    __syncthreads();
    if (threadIdx.x == 0) {
        int run = 0;
        for (int i = 0; i < nsb; ++i) { int tv = bpre[i]; bpre[i] = run; run += tv; }
    }
    __syncthreads();
    const int bin = blockIdx.x;
    const int i0 = bin * B;
    const int binstart = scanned[i0] + bpre[i0 >> 10];
    int binend;
    if (bin + 1 < nbins) {
        const int i1 = (bin + 1) * B;
        binend = scanned[i1] + bpre[i1 >> 10];
    } else {
        binend = E;
    }
    int n = binend - binstart;
    if (n > BINCAP) n = BINCAP;   // statistically impossible; safety clamp

    for (int i = threadIdx.x; i < n; i += 256) eb[i] = binned[binstart + i];
    ldeg[threadIdx.x] = 0;
    __syncthreads();
    for (int i = threadIdx.x; i < n; i += 256)
        atomicAdd(&ldeg[eb[i].y & 255], 1);
    __syncthreads();
    const int v = ldeg[threadIdx.x];
    lscan[threadIdx.x] = v;
    __syncthreads();
    #pragma unroll
    for (int off = 1; off < 256; off <<= 1) {
        int t = threadIdx.x >= off ? lscan[threadIdx.x - off] : 0;
        __syncthreads();
        lscan[threadIdx.x] += t;
        __syncthreads();
    }
    const int excl = lscan[threadIdx.x] - v;
    lcur[threadIdx.x] = excl;
    const int d = (bin << 8) + threadIdx.x;
    if (d < N) {
        rowstart[d] = binstart + excl;
        rowend[d]   = binstart + excl + v;
    }
    __syncthreads();
    for (int i = threadIdx.x; i < n; i += 256) {
        const int lp = atomicAdd(&lcur[eb[i].y & 255], 1);  // LDS atomic
        bucket[binstart + lp] = eb[i].x;
    }
}

// ---------------------------------------------------------------------------
// GAT aggregation, 16 lanes per dst, DEPTH-4 gather pipeline.
// Epilogue bakes +bias_g and leaky(0.01).
// ---------------------------------------------------------------------------
__global__ __launch_bounds__(256) void k_gat(
    const int* __restrict__ bucket,
    const int* __restrict__ rowstart, const int* __restrict__ rowend,
    const float* __restrict__ asrc, const float* __restrict__ adst,
    const unsigned short* __restrict__ hfeat,
    const float* __restrict__ bias_g,
    unsigned short* __restrict__ outbf, int N)
{
    const int wave = threadIdx.x >> 6;
    const int lane = threadIdx.x & 63;
    const int g    = lane >> 4;          // dst-group within wave (0..3)
    const int gl   = lane & 15;          // lane within group
    const int h    = gl >> 2;            // head 0..3
    const int d    = blockIdx.x * 16 + wave * 4 + g;

    int start = 0, end = 0;
    float a_d = 0.f;
    if (d < N) {
        start = rowstart[d];
        end   = rowend[d];
        a_d   = adst[(size_t)d * 4 + h];
    }
    const unsigned int chb = (unsigned int)(gl << 3);   // channel offset (elems)
    const unsigned short* hbase = hfeat + chb;

    float acc[8] = {0.f, 0.f, 0.f, 0.f, 0.f, 0.f, 0.f, 0.f};
    float denom = 0.f;

    int j = start;
    for (; j + 4 <= end; j += 4) {
        // issue all independent loads first: 4 idx, 4 logits, 4 rows
        const int s0 = bucket[j];
        const int s1 = bucket[j + 1];
        const int s2 = bucket[j + 2];
        const int s3 = bucket[j + 3];
        const float as0 = asrc[((size_t)s0 << 2) + h];
        const float as1 = asrc[((size_t)s1 << 2) + h];
        const float as2 = asrc[((size_t)s2 << 2) + h];
        const float as3 = asrc[((size_t)s3 << 2) + h];
        const uint4 hp0 = *(const uint4*)(hbase + ((unsigned int)s0 << 7));
        const uint4 hp1 = *(const uint4*)(hbase + ((unsigned int)s1 << 7));
        const uint4 hp2 = *(const uint4*)(hbase + ((unsigned int)s2 << 7));
        const uint4 hp3 = *(const uint4*)(hbase + ((unsigned int)s3 << 7));
        float a0 = as0 + a_d; a0 = a0 >= 0.f ? a0 : 0.2f * a0;
        float a1 = as1 + a_d; a1 = a1 >= 0.f ? a1 : 0.2f * a1;
        float a2 = as2 + a_d; a2 = a2 >= 0.f ? a2 : 0.2f * a2;
        float a3 = as3 + a_d; a3 = a3 >= 0.f ? a3 : 0.2f * a3;
        const float w0 = __expf(a0), w1 = __expf(a1);
        const float w2 = __expf(a2), w3 = __expf(a3);
        denom += (w0 + w1) + (w2 + w3);
        acc[0] += w0 * b2f((unsigned short)(hp0.x & 0xFFFFu)) + w1 * b2f((unsigned short)(hp1.x & 0xFFFFu))
                + w2 * b2f((unsigned short)(hp2.x & 0xFFFFu)) + w3 * b2f((unsigned short)(hp3.x & 0xFFFFu));
        acc[1] += w0 * b2f((unsigned short)(hp0.x >> 16))     + w1 * b2f((unsigned short)(hp1.x >> 16))
                + w2 * b2f((unsigned short)(hp2.x >> 16))     + w3 * b2f((unsigned short)(hp3.x >> 16));
        acc[2] += w0 * b2f((unsigned short)(hp0.y & 0xFFFFu)) + w1 * b2f((unsigned short)(hp1.y & 0xFFFFu))
                + w2 * b2f((unsigned short)(hp2.y & 0xFFFFu)) + w3 * b2f((unsigned short)(hp3.y & 0xFFFFu));
        acc[3] += w0 * b2f((unsigned short)(hp0.y >> 16))     + w1 * b2f((unsigned short)(hp1.y >> 16))
                + w2 * b2f((unsigned short)(hp2.y >> 16))     + w3 * b2f((unsigned short)(hp3.y >> 16));
        acc[4] += w0 * b2f((unsigned short)(hp0.z & 0xFFFFu)) + w1 * b2f((unsigned short)(hp1.z & 0xFFFFu))
                + w2 * b2f((unsigned short)(hp2.z & 0xFFFFu)) + w3 * b2f((unsigned short)(hp3.z & 0xFFFFu));
        acc[5] += w0 * b2f((unsigned short)(hp0.z >> 16))     + w1 * b2f((unsigned short)(hp1.z >> 16))
                + w2 * b2f((unsigned short)(hp2.z >> 16))     + w3 * b2f((unsigned short)(hp3.z >> 16));
        acc[6] += w0 * b2f((unsigned short)(hp0.w & 0xFFFFu)) + w1 * b2f((unsigned short)(hp1.w & 0xFFFFu))
                + w2 * b2f((unsigned short)(hp2.w & 0xFFFFu)) + w3 * b2f((unsigned short)(hp3.w & 0xFFFFu));
        acc[7] += w0 * b2f((unsigned short)(hp0.w >> 16))     + w1 * b2f((unsigned short)(hp1.w >> 16))
                + w2 * b2f((unsigned short)(hp2.w >> 16))     + w3 * b2f((unsigned short)(hp3.w >> 16));
    }
    for (; j < end; ++j) {
        const int s0 = bucket[j];
        const float as0 = asrc[((size_t)s0 << 2) + h];
        const uint4 hp0 = *(const uint4*)(hbase + ((unsigned int)s0 << 7));
        float a0 = as0 + a_d; a0 = a0 >= 0.f ? a0 : 0.2f * a0;
        const float w0 = __expf(a0);
        denom += w0;
        acc[0] += w0 * b2f((unsigned short)(hp0.x & 0xFFFFu));
        acc[1] += w0 * b2f((unsigned short)(hp0.x >> 16));
        acc[2] += w0 * b2f((unsigned short)(hp0.y & 0xFFFFu));
        acc[3] += w0 * b2f((unsigned short)(hp0.y >> 16));
        acc[4] += w0 * b2f((unsigned short)(hp0.z & 0xFFFFu));
        acc[5] += w0 * b2f((unsigned short)(hp0.z >> 16));
        acc[6] += w0 * b2f((unsigned short)(hp0.w & 0xFFFFu));
        acc[7] += w0 * b2f((unsigned short)(hp0.w >> 16));
    }

    if (d < N) {
        const float inv = 1.f / (denom + 1e-16f);
        const float4 bg0 = *(const float4*)(bias_g + chb);
        const float4 bg1 = *(const float4*)(bias_g + chb + 4);
        const float bg[8] = { bg0.x, bg0.y, bg0.z, bg0.w, bg1.x, bg1.y, bg1.z, bg1.w };
        unsigned short s[8];
        #pragma unroll
        for (int k2 = 0; k2 < 8; ++k2) {
            float v = acc[k2] * inv + bg[k2];
            v = v >= 0.f ? v : 0.01f * v;
            s[k2] = f2b(v);
        }
        uint4 o;
        o.x = ((unsigned int)s[1] << 16) | s[0];
        o.y = ((unsigned int)s[3] << 16) | s[2];
        o.z = ((unsigned int)s[5] << 16) | s[4];
        o.w = ((unsigned int)s[7] << 16) | s[6];
        *(uint4*)(outbf + (((unsigned int)d << 7) + chb)) = o;
    }
}

// ---------------------------------------------------------------------------
// Final GEMM: out = outbf @ W2^T + b2  (unchanged)
// ---------------------------------------------------------------------------
__global__ __launch_bounds__(256) void k_final(
    const unsigned short* __restrict__ gatbf,
    const unsigned short* __restrict__ W2l,
    const float* __restrict__ b2,
    float* __restrict__ out, int N)
{
    __shared__ __align__(16) unsigned short sW[16384];   // 32768 B
    const int t = threadIdx.x;
    const int wave = t >> 6, lane = t & 63, lmod = lane & 15, ldiv = lane >> 4;
    const int rowBase = blockIdx.x * 64;

    uint4 w[8];
    #pragma unroll
    for (int r = 0; r < 8; ++r)
        w[r] = *(const uint4*)(W2l + r * 2048 + t * 8);

    int row = rowBase + wave * 16 + lmod;
    row = min(row, N - 1);
    bf16x8 afr[4];
    #pragma unroll
    for (int ks = 0; ks < 4; ++ks)
        afr[ks] = *(const bf16x8*)(gatbf + (size_t)row * D128 + ks * 32 + ldiv * 8);

    #pragma unroll
    for (int r = 0; r < 8; ++r)
        *(uint4*)&sW[r * 2048 + t * 8] = w[r];
    __syncthreads();

    f32x4 acc[8] = {};
    #pragma unroll
    for (int ct = 0; ct < 8; ++ct) {
        #pragma unroll
        for (int ks = 0; ks < 4; ++ks) {
            bf16x8 bfr = *(const bf16x8*)&sW[(ct * 256 + ks * 64 + lane) * 8];
            acc[ct] = mfma16(afr[ks], bfr, acc[ct]);
        }
    }

    const int orow = rowBase + wave * 16 + ldiv * 4;
    #pragma unroll
    for (int ct = 0; ct < 8; ++ct) {
        const int col = ct * 16 + lmod;
        const float bb = b2[col];
        #pragma unroll
        for (int r = 0; r < 4; ++r)
            if (orow + r < N)
                out[(size_t)(orow + r) * D128 + col] = acc[ct][r] + bb;
    }
}

// ---------------------------------------------------------------------------
extern "C" void kernel_launch(void* const* d_in, const int* in_sizes, int n_in,
                              void* d_out, int out_size, void* d_ws, size_t ws_size,
                              hipStream_t stream)
{
    const float* x    = (const float*)d_in[0];
    const int*   ei   = (const int*)d_in[1];
    // d_in[2] edge_type: unused by forward
    const float* W1   = (const float*)d_in[3];
    const float* b1   = (const float*)d_in[4];
    const float* Wg   = (const float*)d_in[5];
    const float* atts = (const float*)d_in[6];
    const float* attd = (const float*)d_in[7];
    const float* bg   = (const float*)d_in[8];
    const float* W2   = (const float*)d_in[9];
    const float* b2   = (const float*)d_in[10];
    float* out = (float*)d_out;

    const int N = in_sizes[0] / D128;
    const int E = in_sizes[1] / 2;

    const int B     = (E + CHUNK - 1) / CHUNK;       // edge chunks
    const int nbins = (N + 255) >> 8;                // coarse bins
    const int nM    = nbins * B;

    // workspace layout (16B aligned pieces)
    char* ws = (char*)d_ws;
    float* Wc = (float*)ws;                                    // 64 KB
    size_t off = 65536;
    float* bc    = (float*)(ws + off); off += 512;
    float* lbias = (float*)(ws + off); off += 1024;
    unsigned short* Wcat = (unsigned short*)(ws + off); off += 36864;
    unsigned short* W2l  = (unsigned short*)(ws + off); off += 32768;
    unsigned short* xb   = (unsigned short*)(ws + off); off += (size_t)N * D128 * 2;
    unsigned short* hfeat = (unsigned short*)(ws + off); off += (size_t)N * D128 * 2;
    float* asrc = (float*)(ws + off); off += (size_t)N * 4 * 4;
    float* adst = (float*)(ws + off); off += (size_t)N * 4 * 4;
    int* M       = (int*)(ws + off); off += (size_t)nM * 4;
    int* scanned = (int*)(ws + off); off += (size_t)nM * 4;
    int* bsum    = (int*)(ws + off); off += 1024 * 4;
    int2* binned = (int2*)(ws + off); off += (size_t)E * 8;
    int* bucket  = (int*)(ws + off); off += (size_t)E * 4;
    int* rowstart = (int*)(ws + off); off += (size_t)N * 4;
    int* rowend   = (int*)(ws + off); off += (size_t)N * 4;
    unsigned short* outbf = (unsigned short*)(ws + off); off += (size_t)N * D128 * 2;

    // prep: compose weights + dst histogram + bf16(leaky(x))
    k_prep1<<<64 + B + XBB, 256, 0, stream>>>(x, W1, Wg, b1, ei, M, Wc, bc, xb,
                                              N, E, B, nbins);
    k_prep2<<<18, 256, 0, stream>>>(Wc, bc, atts, attd, W2, Wcat, W2l, lbias);

    // single fused GEMM: h + logits
    const int nbg = (N + 63) / 64;
    k_gemm_h<<<nbg, 256, 0, stream>>>(xb, Wcat, lbias, hfeat, asrc, adst, N);

    // CSR build (atomic-free positions; bsum prefix computed locally)
    const int nsb = (nM + 1023) / 1024;
    k_scan1<<<nsb, 1024, 0, stream>>>(M, scanned, bsum, nM);
    kA2<<<B, 256, 0, stream>>>(ei, scanned, bsum, binned, E, B, nbins, nM);
    kB<<<nbins, 256, 0, stream>>>(binned, scanned, bsum, bucket,
                                  rowstart, rowend, E, B, nbins, N, nM);

    // gather-style GAT aggregation (fused softmax + bias_g + leaky), depth-4
    k_gat<<<(N + 15) / 16, 256, 0, stream>>>(bucket, rowstart, rowend,
                                             asrc, adst, hfeat, bg, outbf, N);

    k_final<<<nbg, 256, 0, stream>>>(outbf, W2l, b2, out, N);
}